// Round 4
// baseline (1048.694 us; speedup 1.0000x reference)
//
#include <hip/hip_runtime.h>
#include <stdint.h>

typedef unsigned short u16;
typedef __attribute__((ext_vector_type(8))) short short8;
typedef __attribute__((ext_vector_type(4))) float f32x4;

#define NE   8
#define DIN  2048
#define DOUT 8192
#define NTOK 16384

__device__ __forceinline__ u16 f2bf(float f) {
  uint32_t u = __builtin_bit_cast(uint32_t, f);
  u += 0x7FFFu + ((u >> 16) & 1u);   // RNE (inputs are finite normals)
  return (u16)(u >> 16);
}

__global__ __launch_bounds__(256) void cvt_f32_bf16(const float* __restrict__ src,
                                                    u16* __restrict__ dst, size_t n) {
  size_t i = ((size_t)blockIdx.x * 256 + threadIdx.x) * 8;
  const size_t stride = (size_t)gridDim.x * 256 * 8;
  for (; i < n; i += stride) {
    f32x4 a = *(const f32x4*)(src + i);
    f32x4 b = *(const f32x4*)(src + i + 4);
    short8 o;
    o[0] = (short)f2bf(a[0]); o[1] = (short)f2bf(a[1]);
    o[2] = (short)f2bf(a[2]); o[3] = (short)f2bf(a[3]);
    o[4] = (short)f2bf(b[0]); o[5] = (short)f2bf(b[1]);
    o[6] = (short)f2bf(b[2]); o[7] = (short)f2bf(b[3]);
    *(short8*)(dst + i) = o;
  }
}

#define GLOAD_LDS16(g, l) __builtin_amdgcn_global_load_lds( \
    (const __attribute__((address_space(1))) void*)(g),     \
    (__attribute__((address_space(3))) void*)(l), 16, 0, 0)

// ---------------------------------------------------------------------------
// 256x256 tile, BK=64, 8 waves (2M x 4N), per-wave 128x64 output.
// r4 schedule: 4 phases/K-tile, ONE barrier each (was 8), with cross-phase
// ds_read look-ahead so LDS servicing overlaps the MFMA clusters:
//   P1: [boundary reads ax(kh0),bp] stageA0 MM(ax,bp) [bq] vmcnt(2) bar
//   P2: [ay(kh1) read-ahead] MM(ax,bq) [cp] stageB0 bar
//   P3: MM(ay,cp) [cq] stageA1 bar
//   P4: MM(ay,cq) stageB1 vmcnt(4) bar
// vmcnt is counted and placed BEFORE the barrier (per-wave own-load confirm,
// then barrier publishes); kh1 reads only after the P1-end barrier. Last tile
// uses vmcnt(0) at P1-end (r2 lesson: no new stages => vmcnt(2) races kh1).
// Swizzle: 16B-granule g ^= (row>>1)&3 on read + pre-swizzled global source,
// linear global_load_lds dest => 0 bank conflicts (measured r3).
// ---------------------------------------------------------------------------
__global__ __launch_bounds__(512, 2) void moe_gemm8(
    const u16* __restrict__ Xb, const u16* __restrict__ Wb,
    const int* __restrict__ counts, const float* __restrict__ bias,
    float* __restrict__ C) {
  extern __shared__ u16 sm[];  // 65536 u16: [buf]*32768 + [B]*16384 + [kh]*8192

  const int tid = threadIdx.x;
  const int l = tid & 63;
  const int wid = tid >> 6;      // 0..7
  const int wr = wid >> 2;       // 0..1
  const int wc = wid & 3;        // 0..3

  // XCD-bijective swizzle: 2048 blocks, 256/XCD == tiles/expert => expert==XCD
  const int id = blockIdx.x;
  const int swz = (id & 7) * 256 + (id >> 3);
  const int e = swz >> 8;
  const int rem = swz & 255;
  const int tn = rem >> 3;       // 0..31 (8 consecutive blocks share B-panel)
  const int tm = rem & 7;        // 0..7

  int off = 0;
  for (int i = 0; i < e; ++i) off += counts[i];
  const int row0 = off + tm * 256;
  const int col0 = tn * 256;
  const size_t wbase = (size_t)e * DOUT * DIN + (size_t)col0 * DIN;

  // -- staging per-lane constants (pre-swizzled global source, linear dest)
  const int rl = l >> 2;                     // row within 16-row slice
  const int q = (l & 3) ^ ((l >> 3) & 3);    // source k-granule (inverse swz)
  const int s0 = wid * 2, s1 = s0 + 1;       // this wave's 2 slices of 16
  const u16* pA0 = Xb + (size_t)(row0 + s0 * 16 + rl) * DIN + q * 8;
  const u16* pA1 = Xb + (size_t)(row0 + s1 * 16 + rl) * DIN + q * 8;
  const u16* pB0 = Wb + wbase + (size_t)(s0 * 16 + rl) * DIN + q * 8;
  const u16* pB1 = Wb + wbase + (size_t)(s1 * 16 + rl) * DIN + q * 8;

  // -- fragment-read per-lane constants (swizzled)
  const int f0 = ((l & 15) >> 1) & 3;
  const int gph = (l >> 4) ^ f0;             // physical granule 0..3
  const int aoff = (wr * 128 + (l & 15)) * 32 + gph * 8;
  const int boff = (wc * 64 + (l & 15)) * 32 + gph * 8;

  f32x4 acc[8][4] = {};
  short8 ax[8], ay[8], bp0, bp1, bq0, bq1, cp0, cp1, cq0, cq1;

#define SMA(buf, kh) (sm + (buf) * 32768 + (kh) * 8192)
#define SMB(buf, kh) (sm + (buf) * 32768 + 16384 + (kh) * 8192)
#define STAGE_A(buf, kt, kh) do { const int ko = (kt) * 64 + (kh) * 32; \
    GLOAD_LDS16(pA0 + ko, SMA(buf, kh) + s0 * 512);                     \
    GLOAD_LDS16(pA1 + ko, SMA(buf, kh) + s1 * 512); } while (0)
#define STAGE_B(buf, kt, kh) do { const int ko = (kt) * 64 + (kh) * 32; \
    GLOAD_LDS16(pB0 + ko, SMB(buf, kh) + s0 * 512);                     \
    GLOAD_LDS16(pB1 + ko, SMB(buf, kh) + s1 * 512); } while (0)
#define LDA8(arr, buf, kh) do { _Pragma("unroll") for (int m = 0; m < 8; ++m) \
    arr[m] = *(const short8*)(SMA(buf, kh) + aoff + m * 512); } while (0)
#define LDB2(v0, v1, buf, kh, n0) do {                          \
    v0 = *(const short8*)(SMB(buf, kh) + boff + (n0) * 512);    \
    v1 = *(const short8*)(SMB(buf, kh) + boff + ((n0) + 1) * 512); } while (0)
#define FENCE() asm volatile("" ::: "memory")
#define BAR() do { FENCE(); __builtin_amdgcn_s_barrier(); FENCE(); } while (0)
#define VMW(N) asm volatile("s_waitcnt vmcnt(" #N ")" ::: "memory")
#define MM2(A, B0, B1, n0) do { __builtin_amdgcn_s_setprio(1); _Pragma("unroll")     \
    for (int m = 0; m < 8; ++m) {                                                    \
      acc[m][n0] = __builtin_amdgcn_mfma_f32_16x16x32_bf16(A[m], B0, acc[m][n0], 0, 0, 0);             \
      acc[m][(n0) + 1] = __builtin_amdgcn_mfma_f32_16x16x32_bf16(A[m], B1, acc[m][(n0) + 1], 0, 0, 0); \
    }                                                                                \
    __builtin_amdgcn_s_setprio(0); } while (0)

  const int NKT = DIN / 64;  // 32 K-tiles

  // prologue: tile 0 staged in consumption order A0,B0,A1,B1; kh0 confirmed.
  STAGE_A(0, 0, 0); STAGE_B(0, 0, 0); STAGE_A(0, 0, 1); STAGE_B(0, 0, 1);
  VMW(4);  // kh0 halves landed; kh1 (4 loads) still in flight
  BAR();

  for (int kt = 0; kt < NKT; kt += 2) {
#define TILE(cur, nxt, t) do {                                          \
    const bool hn = (t) + 1 < NKT;                                      \
    /* P1: boundary reads (kh0 confirmed by prior vmcnt+bar) */         \
    LDA8(ax, cur, 0);                                                   \
    LDB2(bp0, bp1, cur, 0, 0);                                          \
    if (hn) STAGE_A(nxt, (t) + 1, 0);                                   \
    MM2(ax, bp0, bp1, 0);                                               \
    LDB2(bq0, bq1, cur, 0, 2);   /* read-ahead for P2 */                \
    if (hn) VMW(2); else VMW(0); /* confirm own kh1 stages landed */    \
    BAR();                                                              \
    /* P2: kh1 now published; ay read-ahead hides under MM */           \
    LDA8(ay, cur, 1);            /* read-ahead for P3 (8 reads) */      \
    MM2(ax, bq0, bq1, 2);        /* waits only bq -> counted lgkm */    \
    LDB2(cp0, cp1, cur, 1, 0);   /* read-ahead for P3 */                \
    if (hn) STAGE_B(nxt, (t) + 1, 0);                                   \
    BAR();                                                              \
    /* P3 */                                                            \
    MM2(ay, cp0, cp1, 0);                                               \
    LDB2(cq0, cq1, cur, 1, 2);   /* read-ahead for P4 */                \
    if (hn) STAGE_A(nxt, (t) + 1, 1);                                   \
    BAR();                                                              \
    /* P4 */                                                            \
    MM2(ay, cq0, cq1, 2);                                               \
    if (hn) { STAGE_B(nxt, (t) + 1, 1); VMW(4); }                       \
    BAR(); } while (0)
    TILE(0, 1, kt);
    TILE(1, 0, kt + 1);
#undef TILE
  }

  // epilogue: C/D layout col=lane&15, row=(lane>>4)*4+j  [m89]
  const int rb = row0 + wr * 128 + ((l >> 4) << 2);
  const int cb = col0 + wc * 64 + (l & 15);
#pragma unroll
  for (int n = 0; n < 4; ++n) {
    const int col = cb + n * 16;
    const float bv = bias[e * DOUT + col];
#pragma unroll
    for (int m = 0; m < 8; ++m) {
      const int r = rb + m * 16;
#pragma unroll
      for (int j = 0; j < 4; ++j)
        C[(size_t)(r + j) * DOUT + col] = acc[m][n][j] + bv;
    }
  }
}

// ---------------------------------------------------------------------------
// Fallback (ws too small): fused fp32->bf16 staging, 128x128 m97 structure.
// ---------------------------------------------------------------------------
__global__ __launch_bounds__(256) void moe_gemm_fused(
    const float* __restrict__ Xf, const float* __restrict__ Wf,
    const int* __restrict__ counts, const float* __restrict__ bias,
    float* __restrict__ C) {
  __shared__ __align__(16) u16 lds[2][2][128 * 32];

  const int tid = threadIdx.x;
  const int lane = tid & 63;
  const int wid = tid >> 6;
  const int wr = wid >> 1;
  const int wc = wid & 1;

  const int id = blockIdx.x;
  const int swz = (id & 7) * ((int)gridDim.x >> 3) + (id >> 3);
  const int e = swz >> 10;
  const int rem = swz & 1023;
  const int tn = rem >> 4;
  const int tml = rem & 15;

  int off = 0;
  for (int i = 0; i < e; ++i) off += counts[i];
  const int row0 = off + tml * 128;
  const int col0 = tn * 128;
  const size_t wbase = (size_t)e * DOUT * DIN + (size_t)col0 * DIN;

  f32x4 acc[4][4] = {};

  auto stage = [&](int buf, int kt) {
#pragma unroll
    for (int s = 0; s < 2; ++s) {
      int i = s * 256 + tid;
      int r = i >> 2, c = i & 3;
      const float* sa = Xf + (size_t)(row0 + r) * DIN + kt * 32 + c * 8;
      const float* sb = Wf + wbase + (size_t)r * DIN + kt * 32 + c * 8;
      f32x4 a0 = *(const f32x4*)sa;
      f32x4 a1 = *(const f32x4*)(sa + 4);
      f32x4 b0 = *(const f32x4*)sb;
      f32x4 b1 = *(const f32x4*)(sb + 4);
      short8 va, vb;
#pragma unroll
      for (int j = 0; j < 4; ++j) {
        va[j] = (short)f2bf(a0[j]); va[j + 4] = (short)f2bf(a1[j]);
        vb[j] = (short)f2bf(b0[j]); vb[j + 4] = (short)f2bf(b1[j]);
      }
      *(short8*)&lds[buf][0][i * 8] = va;
      *(short8*)&lds[buf][1][i * 8] = vb;
    }
  };

  auto compute = [&](int buf) {
    const int kc = lane >> 4;
    const int rr = lane & 15;
    short8 a[4], b[4];
    const u16* lA = lds[buf][0];
    const u16* lB = lds[buf][1];
#pragma unroll
    for (int m = 0; m < 4; ++m)
      a[m] = *(const short8*)(lA + (wr * 64 + m * 16 + rr) * 32 + kc * 8);
#pragma unroll
    for (int n = 0; n < 4; ++n)
      b[n] = *(const short8*)(lB + (wc * 64 + n * 16 + rr) * 32 + kc * 8);
#pragma unroll
    for (int m = 0; m < 4; ++m)
#pragma unroll
      for (int n = 0; n < 4; ++n)
        acc[m][n] = __builtin_amdgcn_mfma_f32_16x16x32_bf16(a[m], b[n], acc[m][n], 0, 0, 0);
  };

  stage(0, 0);
  for (int kt = 0; kt < DIN / 32; ++kt) {
    __syncthreads();
    if (kt + 1 < DIN / 32) stage((kt + 1) & 1, kt + 1);
    compute(kt & 1);
  }

  const int rbase = row0 + wr * 64;
  const int cbase = col0 + wc * 64;
#pragma unroll
  for (int n = 0; n < 4; ++n) {
    const int col = cbase + n * 16 + (lane & 15);
    const float bv = bias[e * DOUT + col];
#pragma unroll
    for (int m = 0; m < 4; ++m) {
      const int r0 = rbase + m * 16 + (lane >> 4) * 4;
#pragma unroll
      for (int j = 0; j < 4; ++j)
        C[(size_t)(r0 + j) * DOUT + col] = acc[m][n][j] + bv;
    }
  }
}

extern "C" void kernel_launch(void* const* d_in, const int* in_sizes, int n_in,
                              void* d_out, int out_size, void* d_ws, size_t ws_size,
                              hipStream_t stream) {
  const float* inp = (const float*)d_in[0];
  const int* counts = (const int*)d_in[1];
  const float* weight = (const float*)d_in[2];
  const float* bias = (const float*)d_in[3];
  float* out = (float*)d_out;

  const size_t nx = (size_t)NTOK * DIN;
  const size_t nw = (size_t)NE * DOUT * DIN;
  const size_t need = (nx + nw) * sizeof(u16);

  if (ws_size >= need) {
    u16* xb = (u16*)d_ws;
    u16* wb = xb + nx;
    cvt_f32_bf16<<<2048, 256, 0, stream>>>(inp, xb, nx);
    cvt_f32_bf16<<<2048, 256, 0, stream>>>(weight, wb, nw);
    const int grid = (NTOK / 256) * (DOUT / 256);  // 2048
    moe_gemm8<<<grid, 512, 131072, stream>>>(xb, wb, counts, bias, out);
  } else {
    const int grid = (NTOK / 128) * (DOUT / 128);  // 8192
    moe_gemm_fused<<<grid, 256, 0, stream>>>(inp, weight, counts, bias, out);
  }
}

// Round 5
// 864.053 us; speedup vs baseline: 1.2137x; 1.2137x over previous
//
#include <hip/hip_runtime.h>
#include <stdint.h>

typedef unsigned short u16;
typedef __attribute__((ext_vector_type(8))) short short8;
typedef __attribute__((ext_vector_type(4))) float f32x4;
typedef __attribute__((ext_vector_type(16))) float f32x16;

#define NE   8
#define DIN  2048
#define DOUT 8192
#define NTOK 16384

__device__ __forceinline__ u16 f2bf(float f) {
  uint32_t u = __builtin_bit_cast(uint32_t, f);
  u += 0x7FFFu + ((u >> 16) & 1u);   // RNE (inputs are finite normals)
  return (u16)(u >> 16);
}

__global__ __launch_bounds__(256) void cvt_f32_bf16(const float* __restrict__ src,
                                                    u16* __restrict__ dst, size_t n) {
  size_t i = ((size_t)blockIdx.x * 256 + threadIdx.x) * 8;
  const size_t stride = (size_t)gridDim.x * 256 * 8;
  for (; i < n; i += stride) {
    f32x4 a = *(const f32x4*)(src + i);
    f32x4 b = *(const f32x4*)(src + i + 4);
    short8 o;
    o[0] = (short)f2bf(a[0]); o[1] = (short)f2bf(a[1]);
    o[2] = (short)f2bf(a[2]); o[3] = (short)f2bf(a[3]);
    o[4] = (short)f2bf(b[0]); o[5] = (short)f2bf(b[1]);
    o[6] = (short)f2bf(b[2]); o[7] = (short)f2bf(b[3]);
    *(short8*)(dst + i) = o;
  }
}

#define GLOAD_LDS16(g, l) __builtin_amdgcn_global_load_lds( \
    (const __attribute__((address_space(1))) void*)(g),     \
    (__attribute__((address_space(3))) void*)(l), 16, 0, 0)

// ---------------------------------------------------------------------------
// r5: r3's proven phase skeleton (reads+stage BEFORE barrier, MFMA after,
// 8 barriers/K-tile — r4's coarsening regressed 38%, reverted) with:
//  (a) 32x32x16 MFMA (ceiling 2495 vs 2075 TF; 32 vs 64 MFMA/K-tile).
//      A/B frag: row = l&31, k-granule = l>>5.  C/D: col=lane&31,
//      row=(reg&3)+8*(reg>>2)+4*(lane>>5)  [m74/m101 verified].
//  (b) deeper vmcnt slack: stage A0B0(t+1)@ph1, A1B1(t+1)@ph2;
//      VMW(8)@ph2 (kh1 slack 4 phases), VMW(4)@ph4 (kh0 slack 3);
//      last tile: VMW(0)@ph2 (r2 lesson: counted wait == no-op race).
// LDS: [buf][A/B][kh][256 rows][32 k] bf16, 128 KiB, double buffered.
// Swizzle: stored phys 16B-granule d of row r holds logical d^((r>>1)&3);
// staging source q=(l&3)^((l>>3)&3) (unchanged), read phys=g^((l>>1)&3).
// 8 lanes per 4-bank group => conflict-free (r3 measured 0).
// ---------------------------------------------------------------------------
__global__ __launch_bounds__(512, 2) void moe_gemm8(
    const u16* __restrict__ Xb, const u16* __restrict__ Wb,
    const int* __restrict__ counts, const float* __restrict__ bias,
    float* __restrict__ C) {
  extern __shared__ u16 sm[];  // 65536 u16

  const int tid = threadIdx.x;
  const int l = tid & 63;
  const int wid = tid >> 6;      // 0..7
  const int wr = wid >> 2;       // 0..1  (M halves of 128)
  const int wc = wid & 3;        // 0..3  (N quarters of 64)

  // XCD-bijective swizzle: 2048 blocks, 256/XCD == tiles/expert => expert==XCD
  const int id = blockIdx.x;
  const int swz = (id & 7) * 256 + (id >> 3);
  const int e = swz >> 8;
  const int rem = swz & 255;
  const int tn = rem >> 3;       // 0..31 (8 consecutive blocks share B-panel)
  const int tm = rem & 7;        // 0..7

  int off = 0;
  for (int i = 0; i < e; ++i) off += counts[i];
  const int row0 = off + tm * 256;
  const int col0 = tn * 256;
  const size_t wbase = (size_t)e * DOUT * DIN + (size_t)col0 * DIN;

  // -- staging per-lane constants (pre-swizzled global source, linear dest)
  const int rl = l >> 2;                     // row within 16-row slice
  const int q = (l & 3) ^ ((l >> 3) & 3);    // source k-granule (inverse swz)
  const int s0 = wid * 2, s1 = s0 + 1;       // this wave's 2 slices of 16
  const u16* pA0 = Xb + (size_t)(row0 + s0 * 16 + rl) * DIN + q * 8;
  const u16* pA1 = Xb + (size_t)(row0 + s1 * 16 + rl) * DIN + q * 8;
  const u16* pB0 = Wb + wbase + (size_t)(s0 * 16 + rl) * DIN + q * 8;
  const u16* pB1 = Wb + wbase + (size_t)(s1 * 16 + rl) * DIN + q * 8;

  // -- fragment-read per-lane constants (32x32 layout, swizzled)
  const int fsw = (l >> 1) & 3;              // ((row within 32)>>1)&3
  const int p0 = (l >> 5) ^ fsw;             // phys granule, kk=0
  const int p1 = (2 + (l >> 5)) ^ fsw;       // phys granule, kk=1
  const int arow = (wr * 128 + (l & 31)) * 32;
  const int brow = (wc * 64 + (l & 31)) * 32;
  const int aoff0 = arow + p0 * 8, aoff1 = arow + p1 * 8;
  const int boff0 = brow + p0 * 8, boff1 = brow + p1 * 8;

  f32x16 acc[4][2] = {};
  short8 a0[4], a1[4], b0, b1;

#define SMA(buf, kh) (sm + (buf) * 32768 + (kh) * 8192)
#define SMB(buf, kh) (sm + (buf) * 32768 + 16384 + (kh) * 8192)
#define STAGE_A(buf, kt, kh) do { const int ko = (kt) * 64 + (kh) * 32; \
    GLOAD_LDS16(pA0 + ko, SMA(buf, kh) + s0 * 512);                     \
    GLOAD_LDS16(pA1 + ko, SMA(buf, kh) + s1 * 512); } while (0)
#define STAGE_B(buf, kt, kh) do { const int ko = (kt) * 64 + (kh) * 32; \
    GLOAD_LDS16(pB0 + ko, SMB(buf, kh) + s0 * 512);                     \
    GLOAD_LDS16(pB1 + ko, SMB(buf, kh) + s1 * 512); } while (0)
#define LDA(buf, kh) do { _Pragma("unroll") for (int mf = 0; mf < 4; ++mf) { \
    a0[mf] = *(const short8*)(SMA(buf, kh) + aoff0 + mf * 1024);             \
    a1[mf] = *(const short8*)(SMA(buf, kh) + aoff1 + mf * 1024); } } while (0)
#define LDB(buf, kh, nf) do {                                     \
    b0 = *(const short8*)(SMB(buf, kh) + boff0 + (nf) * 1024);    \
    b1 = *(const short8*)(SMB(buf, kh) + boff1 + (nf) * 1024); } while (0)
#define FENCE() asm volatile("" ::: "memory")
#define BAR() do { FENCE(); __builtin_amdgcn_s_barrier(); FENCE(); } while (0)
#define VMW(N) asm volatile("s_waitcnt vmcnt(" #N ")" ::: "memory")
#define MM(nf) do { __builtin_amdgcn_s_setprio(1);                                     \
    _Pragma("unroll") for (int mf = 0; mf < 4; ++mf)                                   \
      acc[mf][nf] = __builtin_amdgcn_mfma_f32_32x32x16_bf16(a0[mf], b0, acc[mf][nf], 0, 0, 0); \
    _Pragma("unroll") for (int mf = 0; mf < 4; ++mf)                                   \
      acc[mf][nf] = __builtin_amdgcn_mfma_f32_32x32x16_bf16(a1[mf], b1, acc[mf][nf], 0, 0, 0); \
    __builtin_amdgcn_s_setprio(0); } while (0)

  const int NKT = DIN / 64;  // 32 K-tiles

  // prologue: tile 0 fully staged; confirm kh0 (4 newest = kh1 stay in flight)
  STAGE_A(0, 0, 0); STAGE_B(0, 0, 0); STAGE_A(0, 0, 1); STAGE_B(0, 0, 1);
  VMW(4);
  BAR();

  for (int kt = 0; kt < NKT; kt += 2) {
#define TILE(cur, nxt, t) do {                                          \
    const bool hn = (t) + 1 < NKT;                                      \
    /* ph1: kh0, nf0 — reads+stage BEFORE bar, MFMA after (r3 pattern) */\
    LDA(cur, 0); LDB(cur, 0, 0);                                        \
    if (hn) { STAGE_A(nxt, (t) + 1, 0); STAGE_B(nxt, (t) + 1, 0); }     \
    BAR(); MM(0); BAR();                                                \
    /* ph2: kh0, nf1 */                                                 \
    LDB(cur, 0, 1);                                                     \
    if (hn) { STAGE_A(nxt, (t) + 1, 1); STAGE_B(nxt, (t) + 1, 1);       \
              VMW(8); /* confirm this tile's kh1 (slack 4 phases) */ }  \
    else VMW(0);      /* last tile: counted wait would be a no-op */    \
    BAR(); MM(1); BAR();                                                \
    /* ph3: kh1, nf0 */                                                 \
    LDA(cur, 1); LDB(cur, 1, 0);                                        \
    BAR(); MM(0); BAR();                                                \
    /* ph4: kh1, nf1 */                                                 \
    LDB(cur, 1, 1);                                                     \
    if (hn) VMW(4);   /* confirm next tile's kh0 (slack 3 phases) */    \
    BAR(); MM(1); BAR(); } while (0)
    TILE(0, 1, kt);
    TILE(1, 0, kt + 1);
#undef TILE
  }

  // epilogue: C/D 32x32: col = lane&31, row = (g&3) + 8*(g>>2) + 4*(l>>5)
  const int rb = row0 + wr * 128 + 4 * (l >> 5);
  const int cb = col0 + wc * 64 + (l & 31);
#pragma unroll
  for (int mf = 0; mf < 4; ++mf) {
#pragma unroll
    for (int nf = 0; nf < 2; ++nf) {
      const int col = cb + nf * 32;
      const float bv = bias[e * DOUT + col];
#pragma unroll
      for (int g = 0; g < 16; ++g) {
        const int row = rb + mf * 32 + (g & 3) + 8 * (g >> 2);
        C[(size_t)row * DOUT + col] = acc[mf][nf][g] + bv;
      }
    }
  }
}

// ---------------------------------------------------------------------------
// Fallback (ws too small): fused fp32->bf16 staging, 128x128 m97 structure.
// ---------------------------------------------------------------------------
__global__ __launch_bounds__(256) void moe_gemm_fused(
    const float* __restrict__ Xf, const float* __restrict__ Wf,
    const int* __restrict__ counts, const float* __restrict__ bias,
    float* __restrict__ C) {
  __shared__ __align__(16) u16 lds[2][2][128 * 32];

  const int tid = threadIdx.x;
  const int lane = tid & 63;
  const int wid = tid >> 6;
  const int wr = wid >> 1;
  const int wc = wid & 1;

  const int id = blockIdx.x;
  const int swz = (id & 7) * ((int)gridDim.x >> 3) + (id >> 3);
  const int e = swz >> 10;
  const int rem = swz & 1023;
  const int tn = rem >> 4;
  const int tml = rem & 15;

  int off = 0;
  for (int i = 0; i < e; ++i) off += counts[i];
  const int row0 = off + tml * 128;
  const int col0 = tn * 128;
  const size_t wbase = (size_t)e * DOUT * DIN + (size_t)col0 * DIN;

  f32x4 acc[4][4] = {};

  auto stage = [&](int buf, int kt) {
#pragma unroll
    for (int s = 0; s < 2; ++s) {
      int i = s * 256 + tid;
      int r = i >> 2, c = i & 3;
      const float* sa = Xf + (size_t)(row0 + r) * DIN + kt * 32 + c * 8;
      const float* sb = Wf + wbase + (size_t)r * DIN + kt * 32 + c * 8;
      f32x4 a0 = *(const f32x4*)sa;
      f32x4 a1 = *(const f32x4*)(sa + 4);
      f32x4 b0 = *(const f32x4*)sb;
      f32x4 b1 = *(const f32x4*)(sb + 4);
      short8 va, vb;
#pragma unroll
      for (int j = 0; j < 4; ++j) {
        va[j] = (short)f2bf(a0[j]); va[j + 4] = (short)f2bf(a1[j]);
        vb[j] = (short)f2bf(b0[j]); vb[j + 4] = (short)f2bf(b1[j]);
      }
      *(short8*)&lds[buf][0][i * 8] = va;
      *(short8*)&lds[buf][1][i * 8] = vb;
    }
  };

  auto compute = [&](int buf) {
    const int kc = lane >> 4;
    const int rr = lane & 15;
    short8 a[4], b[4];
    const u16* lA = lds[buf][0];
    const u16* lB = lds[buf][1];
#pragma unroll
    for (int m = 0; m < 4; ++m)
      a[m] = *(const short8*)(lA + (wr * 64 + m * 16 + rr) * 32 + kc * 8);
#pragma unroll
    for (int n = 0; n < 4; ++n)
      b[n] = *(const short8*)(lB + (wc * 64 + n * 16 + rr) * 32 + kc * 8);
#pragma unroll
    for (int m = 0; m < 4; ++m)
#pragma unroll
      for (int n = 0; n < 4; ++n)
        acc[m][n] = __builtin_amdgcn_mfma_f32_16x16x32_bf16(a[m], b[n], acc[m][n], 0, 0, 0);
  };

  stage(0, 0);
  for (int kt = 0; kt < DIN / 32; ++kt) {
    __syncthreads();
    if (kt + 1 < DIN / 32) stage((kt + 1) & 1, kt + 1);
    compute(kt & 1);
  }

  const int rbase = row0 + wr * 64;
  const int cbase = col0 + wc * 64;
#pragma unroll
  for (int n = 0; n < 4; ++n) {
    const int col = cbase + n * 16 + (lane & 15);
    const float bv = bias[e * DOUT + col];
#pragma unroll
    for (int m = 0; m < 4; ++m) {
      const int r0 = rbase + m * 16 + (lane >> 4) * 4;
#pragma unroll
      for (int j = 0; j < 4; ++j)
        C[(size_t)(r0 + j) * DOUT + col] = acc[m][n][j] + bv;
    }
  }
}

extern "C" void kernel_launch(void* const* d_in, const int* in_sizes, int n_in,
                              void* d_out, int out_size, void* d_ws, size_t ws_size,
                              hipStream_t stream) {
  const float* inp = (const float*)d_in[0];
  const int* counts = (const int*)d_in[1];
  const float* weight = (const float*)d_in[2];
  const float* bias = (const float*)d_in[3];
  float* out = (float*)d_out;

  const size_t nx = (size_t)NTOK * DIN;
  const size_t nw = (size_t)NE * DOUT * DIN;
  const size_t need = (nx + nw) * sizeof(u16);

  if (ws_size >= need) {
    u16* xb = (u16*)d_ws;
    u16* wb = xb + nx;
    cvt_f32_bf16<<<2048, 256, 0, stream>>>(inp, xb, nx);
    cvt_f32_bf16<<<2048, 256, 0, stream>>>(weight, wb, nw);
    const int grid = (NTOK / 256) * (DOUT / 256);  // 2048
    moe_gemm8<<<grid, 512, 131072, stream>>>(xb, wb, counts, bias, out);
  } else {
    const int grid = (NTOK / 128) * (DOUT / 128);  // 8192
    moe_gemm_fused<<<grid, 256, 0, stream>>>(inp, weight, counts, bias, out);
  }
}